// Round 9
// baseline (261.224 us; speedup 1.0000x reference)
//
#include <hip/hip_runtime.h>

#define BB 8
#define NN 8192
#define NPOINT 2048
#define NSAMPLE 64
#define CIN 64
#define RADIUS 0.2f
#define R2 (RADIUS * RADIUS)

// d_out layout (flat floats, reference return order)
#define OFF_NEWXYZ 0
#define OFF_FEAT (BB * NPOINT * 3)
#define OFF_INDS (OFF_FEAT + BB * NPOINT * 128)
#define OFF_IDX (OFF_INDS + BB * NPOINT)

typedef _Float16 half8 __attribute__((ext_vector_type(8)));
typedef __fp16 f16x2 __attribute__((ext_vector_type(2)));
typedef float floatx16 __attribute__((ext_vector_type(16)));

// Per-wave LDS slice (halves). P0=88 (K0=80+pad, stride 176B = 12 banks mod 32
// -> conflict-free b128 reads). P1=72 (144B = 4 banks mod 32 -> conflict-free).
// R6-proven layout: scalar C-writes, 94K conflicts, best measured mlp (83us).
#define P0 88
#define P1 72
#define X_LOC 0
#define H_LOC (64 * P0)                 // 5632
#define XH_WAVE (64 * P0 + 64 * P1)     // 10240 halves = 20480 B per wave
// one-time weight staging (block-shared, overlaps the wave slices):
#define WT0_S 0
#define WT1_S (64 * P0)
#define WT2_S (64 * P0 + 64 * P1)       // fits in 2*XH_WAVE

#define QPW 8  // queries per wave; 1024 blocks, no tail

// ---------------------------------------------------------------------------
// Fused kernel: per query (one wave owns it end-to-end):
//   1) ball-query scan (ballot + ordered LDS scatter; idx stays in registers)
//   2) gather + stage X (fp16, pkrtz packed)
//   3) 3-layer MFMA MLP + fused maxpool (R6 structure verbatim)
// 128-thread block = 2 independent waves, private LDS slices, no barriers
// after the one-time weight staging.
// ---------------------------------------------------------------------------
__global__ __launch_bounds__(128, 2) void fused_sa(
    const float* __restrict__ xyz, const float* __restrict__ features,
    const int* __restrict__ inds,
    const float* __restrict__ w0, const float* __restrict__ s0,
    const float* __restrict__ t0, const float* __restrict__ w1,
    const float* __restrict__ s1, const float* __restrict__ t1,
    const float* __restrict__ w2, const float* __restrict__ s2,
    const float* __restrict__ t2, float* __restrict__ out) {
  __shared__ _Float16 sm[2 * XH_WAVE];  // 40960 B -> 4 blocks/CU, 8 waves/CU
  const int tid = threadIdx.x;
  const int w = tid >> 6;
  const int l = tid & 63;
  const int l31 = l & 31;
  const int h5 = l >> 5;
  const int koff = h5 * 8;  // fragment k-offset in halves

  // ---- stage folded weights into fragment-layout LDS (block-wide, once) ----
  {
    const int d = tid >> 1, hf = tid & 1;
    const float sd0 = s0[d], td0 = t0[d], sd1 = s1[d];
#pragma unroll
    for (int j = 0; j < 44; ++j) {
      const int c = hf * 44 + j;
      float v = 0.0f;
      if (c < 64) v = w0[(3 + c) * 64 + d] * sd0;        // feature channels
      else if (c < 67) v = w0[(c - 64) * 64 + d] * sd0;  // xyz channels
      else if (c == 67) v = td0;                         // bias channel
      sm[WT0_S + d * P0 + c] = (_Float16)v;
    }
#pragma unroll
    for (int j = 0; j < 32; ++j) {
      const int c = hf * 32 + j;
      sm[WT1_S + d * P1 + c] = (_Float16)(w1[c * 64 + d] * sd1);
    }
    const int ch = tid;  // 0..127
    const float sch = s2[ch];
#pragma unroll
    for (int c = 0; c < 64; ++c)
      sm[WT2_S + ch * P1 + c] = (_Float16)(w2[c * 128 + ch] * sch);
  }
  __syncthreads();

  // ---- hoist weight fragments + t vectors into registers ----
  half8 b0f[2][5], b1f[2][4], b2f[4][4];
#pragma unroll
  for (int nt = 0; nt < 2; ++nt)
#pragma unroll
    for (int ks = 0; ks < 5; ++ks)
      b0f[nt][ks] =
          *(const half8*)&sm[WT0_S + (nt * 32 + l31) * P0 + ks * 16 + koff];
#pragma unroll
  for (int nt = 0; nt < 2; ++nt)
#pragma unroll
    for (int ks = 0; ks < 4; ++ks)
      b1f[nt][ks] =
          *(const half8*)&sm[WT1_S + (nt * 32 + l31) * P1 + ks * 16 + koff];
#pragma unroll
  for (int ct = 0; ct < 4; ++ct)
#pragma unroll
    for (int ks = 0; ks < 4; ++ks)
      b2f[ct][ks] =
          *(const half8*)&sm[WT2_S + (ct * 32 + l31) * P1 + ks * 16 + koff];
  const float t1v0 = t1[l31];
  const float t1v1 = t1[32 + l31];
  float t2v[4];
#pragma unroll
  for (int ct = 0; ct < 4; ++ct) t2v[ct] = t2[ct * 32 + l31];
  __syncthreads();  // all fragment reads done before slices overwrite region

  _Float16* xbuf = sm + w * XH_WAVE + X_LOC;
  _Float16* hbuf = sm + w * XH_WAVE + H_LOC;
  int* idxbuf = (int*)hbuf;  // scan scatter area; dead between queries
  // zero X K-pad halves 72..79 once (64..71 rewritten per query)
  {
    half8 z = {};
    *(half8*)&xbuf[l * P0 + 72] = z;
  }

  const int wq0 = (blockIdx.x * 2 + w) * QPW;
#pragma unroll 1
  for (int qi = 0; qi < QPW; ++qi) {
    const int q = wq0 + qi;
    const int b = q >> 11;  // NPOINT = 2048
    const float* xb = xyz + (size_t)b * NN * 3;

    // ================= phase 1: ball-query scan =================
    const int ind = inds[q];
    const float cx = xb[ind * 3 + 0], cy = xb[ind * 3 + 1],
                cz = xb[ind * 3 + 2];
    if (l == 0) {
      out[OFF_NEWXYZ + (size_t)q * 3 + 0] = cx;
      out[OFF_NEWXYZ + (size_t)q * 3 + 1] = cy;
      out[OFF_NEWXYZ + (size_t)q * 3 + 2] = cz;
      out[OFF_INDS + q] = (float)ind;
    }
    // distance formula must stay qq + nn - 2*dot (reference rounding):
    // borderline hit flips would corrupt the idx output.
    const float qq = cx * cx + cy * cy + cz * cz;

    int cnt = 0;
    const float* pw = xb + (size_t)l * 3;  // lane's candidate base
#pragma unroll 1
    for (int j0 = 0; j0 < NN; j0 += 256) {
      const float* pj = pw + (size_t)j0 * 3;
#pragma unroll
      for (int k = 0; k < 4; ++k) {  // k-major preserves point order
        const float px = pj[k * 192 + 0];
        const float py = pj[k * 192 + 1];
        const float pz = pj[k * 192 + 2];
        const float nn_ = px * px + py * py + pz * pz;
        const float dot = cx * px + cy * py + cz * pz;
        const bool hit = (qq + nn_ - 2.0f * dot) < R2;
        const unsigned long long m = __ballot(hit);
        if (hit) {
          const int pos = cnt + (int)__popcll(m & ((1ull << l) - 1ull));
          if (pos < NSAMPLE) idxbuf[pos] = j0 + k * 64 + l;
        }
        cnt += (int)__popcll(m);
      }
      if (cnt >= NSAMPLE) break;
    }
    // readback: lane's sample index (pad with first hit; center always hits
    // itself so cnt >= 1 and idxbuf[0] is valid)
    const int vi = idxbuf[l];
    const int v0 = idxbuf[0];
    const int idxs = (l < cnt) ? vi : v0;
    out[OFF_IDX + (size_t)q * NSAMPLE + l] = (float)idxs;  // coalesced

    // ================= phase 2: gather + stage X =================
    const float ppx = xb[idxs * 3 + 0], ppy = xb[idxs * 3 + 1],
                ppz = xb[idxs * 3 + 2];
    const float4* fr =
        (const float4*)(features + ((size_t)b * NN + (size_t)idxs) * CIN);
    float4 f[16];
#pragma unroll
    for (int u = 0; u < 16; ++u) f[u] = fr[u];
#pragma unroll
    for (int u = 0; u < 8; ++u) {
      union {
        half8 v;
        f16x2 p[4];
      } hv;
      hv.p[0] = __builtin_amdgcn_cvt_pkrtz(f[2 * u].x, f[2 * u].y);
      hv.p[1] = __builtin_amdgcn_cvt_pkrtz(f[2 * u].z, f[2 * u].w);
      hv.p[2] = __builtin_amdgcn_cvt_pkrtz(f[2 * u + 1].x, f[2 * u + 1].y);
      hv.p[3] = __builtin_amdgcn_cvt_pkrtz(f[2 * u + 1].z, f[2 * u + 1].w);
      *(half8*)&xbuf[l * P0 + u * 8] = hv.v;
    }
    {
      union {
        half8 v;
        f16x2 p[4];
      } xv;
      xv.p[0] =
          __builtin_amdgcn_cvt_pkrtz((ppx - cx) * 5.0f, (ppy - cy) * 5.0f);
      xv.p[1] = __builtin_amdgcn_cvt_pkrtz((ppz - cz) * 5.0f, 1.0f);  // bias
      xv.p[2] = __builtin_amdgcn_cvt_pkrtz(0.0f, 0.0f);
      xv.p[3] = __builtin_amdgcn_cvt_pkrtz(0.0f, 0.0f);
      *(half8*)&xbuf[l * P0 + 64] = xv.v;
    }

    // ================= phase 3: MLP (R6 structure) =================
    // ---- L0: H0 = relu(X @ W0' + t0) (K=80, bias via channel 67) ----
    {
      half8 xa[2][5];
#pragma unroll
      for (int st = 0; st < 2; ++st)
#pragma unroll
        for (int ks = 0; ks < 5; ++ks)
          xa[st][ks] =
              *(const half8*)&xbuf[(st * 32 + l31) * P0 + ks * 16 + koff];
#pragma unroll
      for (int nt = 0; nt < 2; ++nt)
#pragma unroll
        for (int st = 0; st < 2; ++st) {
          floatx16 acc;
#pragma unroll
          for (int i = 0; i < 16; ++i) acc[i] = 0.0f;
#pragma unroll
          for (int ks = 0; ks < 5; ++ks)
            acc = __builtin_amdgcn_mfma_f32_32x32x16_f16(xa[st][ks],
                                                         b0f[nt][ks], acc,
                                                         0, 0, 0);
#pragma unroll
          for (int reg = 0; reg < 16; ++reg) {
            const int row = st * 32 + (reg & 3) + 8 * (reg >> 2) + 4 * h5;
            hbuf[row * P1 + nt * 32 + l31] = (_Float16)fmaxf(acc[reg], 0.0f);
          }
        }
    }

    // ---- L1: H1 = relu(H0 @ W1' + t1), written into xbuf cols 0..63 ----
    {
      half8 ha[2][4];
#pragma unroll
      for (int st = 0; st < 2; ++st)
#pragma unroll
        for (int ks = 0; ks < 4; ++ks)
          ha[st][ks] =
              *(const half8*)&hbuf[(st * 32 + l31) * P1 + ks * 16 + koff];
#pragma unroll
      for (int nt = 0; nt < 2; ++nt) {
        const float tt = nt ? t1v1 : t1v0;
#pragma unroll
        for (int st = 0; st < 2; ++st) {
          floatx16 acc;
#pragma unroll
          for (int i = 0; i < 16; ++i) acc[i] = 0.0f;
#pragma unroll
          for (int ks = 0; ks < 4; ++ks)
            acc = __builtin_amdgcn_mfma_f32_32x32x16_f16(ha[st][ks],
                                                         b1f[nt][ks], acc,
                                                         0, 0, 0);
#pragma unroll
          for (int reg = 0; reg < 16; ++reg) {
            const int row = st * 32 + (reg & 3) + 8 * (reg >> 2) + 4 * h5;
            xbuf[row * P0 + nt * 32 + l31] =
                (_Float16)fmaxf(acc[reg] + tt, 0.0f);
          }
        }
      }
    }

    // ---- L2: Y = H1 @ W2' (lane owns d2 column), fused maxpool ----
    {
      half8 h1a[2][4];
#pragma unroll
      for (int st = 0; st < 2; ++st)
#pragma unroll
        for (int ks = 0; ks < 4; ++ks)
          h1a[st][ks] =
              *(const half8*)&xbuf[(st * 32 + l31) * P0 + ks * 16 + koff];
#pragma unroll
      for (int ct = 0; ct < 4; ++ct) {
        floatx16 aA, aB;
#pragma unroll
        for (int i = 0; i < 16; ++i) {
          aA[i] = 0.0f;
          aB[i] = 0.0f;
        }
#pragma unroll
        for (int ks = 0; ks < 4; ++ks) {
          aA = __builtin_amdgcn_mfma_f32_32x32x16_f16(h1a[0][ks], b2f[ct][ks],
                                                      aA, 0, 0, 0);
          aB = __builtin_amdgcn_mfma_f32_32x32x16_f16(h1a[1][ks], b2f[ct][ks],
                                                      aB, 0, 0, 0);
        }
        float m = fmaxf(aA[0], aB[0]);
#pragma unroll
        for (int i = 1; i < 16; ++i) m = fmaxf(m, fmaxf(aA[i], aB[i]));
        float v = fmaxf(m + t2v[ct], 0.0f);  // relu(max+t) == max(relu(+t))
        v = fmaxf(v, __shfl_xor(v, 32, 64));  // merge complementary row halves
        if (l < 32) out[OFF_FEAT + (size_t)q * 128 + ct * 32 + l] = v;
      }
    }
  }
}

extern "C" void kernel_launch(void* const* d_in, const int* in_sizes, int n_in,
                              void* d_out, int out_size, void* d_ws,
                              size_t ws_size, hipStream_t stream) {
  const float* xyz = (const float*)d_in[0];
  const float* features = (const float*)d_in[1];
  const int* inds = (const int*)d_in[2];
  const float* w0 = (const float*)d_in[3];
  const float* s0 = (const float*)d_in[4];
  const float* t0 = (const float*)d_in[5];
  const float* w1 = (const float*)d_in[6];
  const float* s1 = (const float*)d_in[7];
  const float* t1 = (const float*)d_in[8];
  const float* w2 = (const float*)d_in[9];
  const float* s2 = (const float*)d_in[10];
  const float* t2 = (const float*)d_in[11];
  float* out = (float*)d_out;

  const int nquery = BB * NPOINT;  // 16384
  // 2 waves/block * QPW queries each -> 1024 blocks = 4 blocks/CU
  fused_sa<<<nquery / (2 * QPW), 128, 0, stream>>>(
      xyz, features, inds, w0, s0, t0, w1, s1, t1, w2, s2, t2, out);
}

// Round 10
// 223.111 us; speedup vs baseline: 1.1708x; 1.1708x over previous
//
#include <hip/hip_runtime.h>

#define BB 8
#define NN 8192
#define NPOINT 2048
#define NSAMPLE 64
#define CIN 64
#define RADIUS 0.2f
#define R2 (RADIUS * RADIUS)

// d_out layout (flat floats, reference return order)
#define OFF_NEWXYZ 0
#define OFF_FEAT (BB * NPOINT * 3)
#define OFF_INDS (OFF_FEAT + BB * NPOINT * 128)
#define OFF_IDX (OFF_INDS + BB * NPOINT)

typedef _Float16 half8 __attribute__((ext_vector_type(8)));
typedef __fp16 f16x2 __attribute__((ext_vector_type(2)));
typedef float floatx16 __attribute__((ext_vector_type(16)));

// Per-wave LDS slice (halves). P0=88 (K0=80+pad, stride 176B = 12 banks mod 32
// -> conflict-free b128 reads). P1=72 (144B = 4 banks mod 32 -> conflict-free).
// R6-proven layout (83us mlp, 94K conflicts).
#define P0 88
#define P1 72
#define X_LOC 0
#define H_LOC (64 * P0)                 // 5632
#define XH_WAVE (64 * P0 + 64 * P1)     // 10240 halves = 20480 B per wave
// one-time weight staging (block-shared, overlaps the wave slices):
#define WT0_S 0
#define WT1_S (64 * P0)
#define WT2_S (64 * P0 + 64 * P1)       // fits in 2*XH_WAVE

#define QPW 8  // queries per wave; 1024 blocks = 4 blocks/CU, no tail

// ---------------------------------------------------------------------------
// Kernel 1: ball query (R8 version). High occupancy (no LDS, 4096 blocks)
// is what hides the scan's serial ballot chain — do NOT fuse into the MLP
// kernel (R9 measured: fusion at 8 waves/CU costs ~110us of exposed latency).
// Distance formula must stay qq + nn - 2*dot (reference rounding).
// ---------------------------------------------------------------------------
__global__ __launch_bounds__(256) void ballq_kernel(
    const float* __restrict__ xyz, const int* __restrict__ inds,
    float* __restrict__ out) {
  const int wq = (blockIdx.x * 256 + threadIdx.x) >> 6;  // query id
  const int lane = threadIdx.x & 63;
  const int b = wq >> 11;  // NPOINT = 2048

  const float* xb = xyz + (size_t)b * NN * 3;
  const int ind = inds[wq];
  const float cx = xb[ind * 3 + 0];
  const float cy = xb[ind * 3 + 1];
  const float cz = xb[ind * 3 + 2];

  if (lane == 0) {
    out[OFF_NEWXYZ + (size_t)wq * 3 + 0] = cx;
    out[OFF_NEWXYZ + (size_t)wq * 3 + 1] = cy;
    out[OFF_NEWXYZ + (size_t)wq * 3 + 2] = cz;
    out[OFF_INDS + wq] = (float)ind;
  }

  const float qq = cx * cx + cy * cy + cz * cz;
  float* myidx = out + OFF_IDX + (size_t)wq * NSAMPLE;

  int cnt = 0;
  float ax[4], ay[4], az[4];
#pragma unroll
  for (int k = 0; k < 4; ++k) {
    const float* p = xb + (size_t)(k * 64 + lane) * 3;
    ax[k] = p[0];
    ay[k] = p[1];
    az[k] = p[2];
  }
  for (int j0 = 0; j0 < NN; j0 += 256) {
    float bx[4] = {0}, by[4] = {0}, bz[4] = {0};
    const int jn = j0 + 256;
    if (jn < NN) {  // prefetch next chunk while ballots run on current
#pragma unroll
      for (int k = 0; k < 4; ++k) {
        const float* p = xb + (size_t)(jn + k * 64 + lane) * 3;
        bx[k] = p[0];
        by[k] = p[1];
        bz[k] = p[2];
      }
    }
#pragma unroll
    for (int k = 0; k < 4; ++k) {  // k-major preserves point order
      const float nn_ = ax[k] * ax[k] + ay[k] * ay[k] + az[k] * az[k];
      const float dot = cx * ax[k] + cy * ay[k] + cz * az[k];
      const bool hit = (qq + nn_ - 2.0f * dot) < R2;
      const unsigned long long m = __ballot(hit);
      if (hit) {
        const int pos = cnt + (int)__popcll(m & ((1ull << lane) - 1ull));
        if (pos < NSAMPLE) myidx[pos] = (float)(j0 + k * 64 + lane);
      }
      cnt += (int)__popcll(m);
    }
    if (cnt >= NSAMPLE) break;
#pragma unroll
    for (int k = 0; k < 4; ++k) {
      ax[k] = bx[k];
      ay[k] = by[k];
      az[k] = bz[k];
    }
  }
  // Pad: center point always hits itself -> cnt >= 1 -> myidx[0] valid.
  const float f0 = myidx[0];
  if (lane >= cnt) myidx[lane] = f0;
}

// ---------------------------------------------------------------------------
// Kernel 2: MFMA MLP (R6 structure) + cross-query software pipeline:
// while query qi runs L0..L2, query qi+1's idx read and feature gather are
// in flight (f[16] float4 held in registers across the MLP — ~230 VGPR,
// within the 256/wave budget of __launch_bounds__(128,2), occupancy intact).
// ---------------------------------------------------------------------------
__global__ __launch_bounds__(128, 2) void mlp_mfma(
    const float* __restrict__ xyz, const float* __restrict__ features,
    const int* __restrict__ inds,
    const float* __restrict__ w0, const float* __restrict__ s0,
    const float* __restrict__ t0, const float* __restrict__ w1,
    const float* __restrict__ s1, const float* __restrict__ t1,
    const float* __restrict__ w2, const float* __restrict__ s2,
    const float* __restrict__ t2, float* __restrict__ out) {
  __shared__ _Float16 sm[2 * XH_WAVE];  // 40960 B -> 4 blocks/CU, 8 waves/CU
  const int tid = threadIdx.x;
  const int w = tid >> 6;
  const int l = tid & 63;
  const int l31 = l & 31;
  const int h5 = l >> 5;
  const int koff = h5 * 8;  // fragment k-offset in halves

  // ---- stage folded weights into fragment-layout LDS (block-wide, once) ----
  {
    const int d = tid >> 1, hf = tid & 1;
    const float sd0 = s0[d], td0 = t0[d], sd1 = s1[d];
#pragma unroll
    for (int j = 0; j < 44; ++j) {
      const int c = hf * 44 + j;
      float v = 0.0f;
      if (c < 64) v = w0[(3 + c) * 64 + d] * sd0;        // feature channels
      else if (c < 67) v = w0[(c - 64) * 64 + d] * sd0;  // xyz channels
      else if (c == 67) v = td0;                         // bias channel
      sm[WT0_S + d * P0 + c] = (_Float16)v;
    }
#pragma unroll
    for (int j = 0; j < 32; ++j) {
      const int c = hf * 32 + j;
      sm[WT1_S + d * P1 + c] = (_Float16)(w1[c * 64 + d] * sd1);
    }
    const int ch = tid;  // 0..127
    const float sch = s2[ch];
#pragma unroll
    for (int c = 0; c < 64; ++c)
      sm[WT2_S + ch * P1 + c] = (_Float16)(w2[c * 128 + ch] * sch);
  }
  __syncthreads();

  // ---- hoist weight fragments + t vectors into registers ----
  half8 b0f[2][5], b1f[2][4], b2f[4][4];
#pragma unroll
  for (int nt = 0; nt < 2; ++nt)
#pragma unroll
    for (int ks = 0; ks < 5; ++ks)
      b0f[nt][ks] =
          *(const half8*)&sm[WT0_S + (nt * 32 + l31) * P0 + ks * 16 + koff];
#pragma unroll
  for (int nt = 0; nt < 2; ++nt)
#pragma unroll
    for (int ks = 0; ks < 4; ++ks)
      b1f[nt][ks] =
          *(const half8*)&sm[WT1_S + (nt * 32 + l31) * P1 + ks * 16 + koff];
#pragma unroll
  for (int ct = 0; ct < 4; ++ct)
#pragma unroll
    for (int ks = 0; ks < 4; ++ks)
      b2f[ct][ks] =
          *(const half8*)&sm[WT2_S + (ct * 32 + l31) * P1 + ks * 16 + koff];
  const float t1v0 = t1[l31];
  const float t1v1 = t1[32 + l31];
  float t2v[4];
#pragma unroll
  for (int ct = 0; ct < 4; ++ct) t2v[ct] = t2[ct * 32 + l31];
  __syncthreads();  // all fragment reads done before slices overwrite region

  _Float16* xbuf = sm + w * XH_WAVE + X_LOC;
  _Float16* hbuf = sm + w * XH_WAVE + H_LOC;
  // zero X K-pad halves 72..79 once (64..71 rewritten per query)
  {
    half8 z = {};
    *(half8*)&xbuf[l * P0 + 72] = z;
  }

  const int wq0 = (blockIdx.x * 2 + w) * QPW;

  // ---- prologue: prefetch query wq0's gather into registers ----
  const float* xb = xyz + (size_t)(wq0 >> 11) * NN * 3;
  float4 f[16];
  float cx, cy, cz, ppx, ppy, ppz;
  {
    const int ind = inds[wq0];
    cx = xb[ind * 3 + 0];
    cy = xb[ind * 3 + 1];
    cz = xb[ind * 3 + 2];
    const int idxs = (int)out[OFF_IDX + (size_t)wq0 * NSAMPLE + l];
    ppx = xb[idxs * 3 + 0];
    ppy = xb[idxs * 3 + 1];
    ppz = xb[idxs * 3 + 2];
    const float4* fr = (const float4*)(features +
                                       ((size_t)(wq0 >> 11) * NN + idxs) * CIN);
#pragma unroll
    for (int u = 0; u < 16; ++u) f[u] = fr[u];
  }

#pragma unroll 1
  for (int qi = 0; qi < QPW; ++qi) {
    const int q = wq0 + qi;

    // ---- stage X from prefetched registers (lane = sample) ----
#pragma unroll
    for (int u = 0; u < 8; ++u) {
      union {
        half8 v;
        f16x2 p[4];
      } hv;
      hv.p[0] = __builtin_amdgcn_cvt_pkrtz(f[2 * u].x, f[2 * u].y);
      hv.p[1] = __builtin_amdgcn_cvt_pkrtz(f[2 * u].z, f[2 * u].w);
      hv.p[2] = __builtin_amdgcn_cvt_pkrtz(f[2 * u + 1].x, f[2 * u + 1].y);
      hv.p[3] = __builtin_amdgcn_cvt_pkrtz(f[2 * u + 1].z, f[2 * u + 1].w);
      *(half8*)&xbuf[l * P0 + u * 8] = hv.v;
    }
    {
      union {
        half8 v;
        f16x2 p[4];
      } xv;
      xv.p[0] =
          __builtin_amdgcn_cvt_pkrtz((ppx - cx) * 5.0f, (ppy - cy) * 5.0f);
      xv.p[1] = __builtin_amdgcn_cvt_pkrtz((ppz - cz) * 5.0f, 1.0f);  // bias
      xv.p[2] = __builtin_amdgcn_cvt_pkrtz(0.0f, 0.0f);
      xv.p[3] = __builtin_amdgcn_cvt_pkrtz(0.0f, 0.0f);
      *(half8*)&xbuf[l * P0 + 64] = xv.v;
    }

    // ---- issue next query's idx + center loads (covered by L0) ----
    const int nq = (qi + 1 < QPW) ? q + 1 : q;  // clamp: redundant reload ok
    const float* nxb = xyz + (size_t)(nq >> 11) * NN * 3;
    const int nind = inds[nq];
    const float fni = out[OFF_IDX + (size_t)nq * NSAMPLE + l];
    const float ncx = nxb[nind * 3 + 0];
    const float ncy = nxb[nind * 3 + 1];
    const float ncz = nxb[nind * 3 + 2];

    // ---- L0: H0 = relu(X @ W0' + t0) (K=80, bias via channel 67) ----
    {
      half8 xa[2][5];
#pragma unroll
      for (int st = 0; st < 2; ++st)
#pragma unroll
        for (int ks = 0; ks < 5; ++ks)
          xa[st][ks] =
              *(const half8*)&xbuf[(st * 32 + l31) * P0 + ks * 16 + koff];
#pragma unroll
      for (int nt = 0; nt < 2; ++nt)
#pragma unroll
        for (int st = 0; st < 2; ++st) {
          floatx16 acc;
#pragma unroll
          for (int i = 0; i < 16; ++i) acc[i] = 0.0f;
#pragma unroll
          for (int ks = 0; ks < 5; ++ks)
            acc = __builtin_amdgcn_mfma_f32_32x32x16_f16(xa[st][ks],
                                                         b0f[nt][ks], acc,
                                                         0, 0, 0);
#pragma unroll
          for (int reg = 0; reg < 16; ++reg) {
            const int row = st * 32 + (reg & 3) + 8 * (reg >> 2) + 4 * h5;
            hbuf[row * P1 + nt * 32 + l31] = (_Float16)fmaxf(acc[reg], 0.0f);
          }
        }
    }

    // ---- issue next query's feature gather (covered by L1+L2) ----
    const int nidxs = (int)fni;
    {
      const float4* nfr = (const float4*)(features +
                                          ((size_t)(nq >> 11) * NN + nidxs) *
                                              CIN);
#pragma unroll
      for (int u = 0; u < 16; ++u) f[u] = nfr[u];
    }
    const float nppx = nxb[nidxs * 3 + 0];
    const float nppy = nxb[nidxs * 3 + 1];
    const float nppz = nxb[nidxs * 3 + 2];

    // ---- L1: H1 = relu(H0 @ W1' + t1), written into xbuf cols 0..63 ----
    {
      half8 ha[2][4];
#pragma unroll
      for (int st = 0; st < 2; ++st)
#pragma unroll
        for (int ks = 0; ks < 4; ++ks)
          ha[st][ks] =
              *(const half8*)&hbuf[(st * 32 + l31) * P1 + ks * 16 + koff];
#pragma unroll
      for (int nt = 0; nt < 2; ++nt) {
        const float tt = nt ? t1v1 : t1v0;
#pragma unroll
        for (int st = 0; st < 2; ++st) {
          floatx16 acc;
#pragma unroll
          for (int i = 0; i < 16; ++i) acc[i] = 0.0f;
#pragma unroll
          for (int ks = 0; ks < 4; ++ks)
            acc = __builtin_amdgcn_mfma_f32_32x32x16_f16(ha[st][ks],
                                                         b1f[nt][ks], acc,
                                                         0, 0, 0);
#pragma unroll
          for (int reg = 0; reg < 16; ++reg) {
            const int row = st * 32 + (reg & 3) + 8 * (reg >> 2) + 4 * h5;
            xbuf[row * P0 + nt * 32 + l31] =
                (_Float16)fmaxf(acc[reg] + tt, 0.0f);
          }
        }
      }
    }

    // ---- L2: Y = H1 @ W2' (lane owns d2 column), fused maxpool ----
    {
      half8 h1a[2][4];
#pragma unroll
      for (int st = 0; st < 2; ++st)
#pragma unroll
        for (int ks = 0; ks < 4; ++ks)
          h1a[st][ks] =
              *(const half8*)&xbuf[(st * 32 + l31) * P0 + ks * 16 + koff];
#pragma unroll
      for (int ct = 0; ct < 4; ++ct) {
        floatx16 aA, aB;
#pragma unroll
        for (int i = 0; i < 16; ++i) {
          aA[i] = 0.0f;
          aB[i] = 0.0f;
        }
#pragma unroll
        for (int ks = 0; ks < 4; ++ks) {
          aA = __builtin_amdgcn_mfma_f32_32x32x16_f16(h1a[0][ks], b2f[ct][ks],
                                                      aA, 0, 0, 0);
          aB = __builtin_amdgcn_mfma_f32_32x32x16_f16(h1a[1][ks], b2f[ct][ks],
                                                      aB, 0, 0, 0);
        }
        float m = fmaxf(aA[0], aB[0]);
#pragma unroll
        for (int i = 1; i < 16; ++i) m = fmaxf(m, fmaxf(aA[i], aB[i]));
        float v = fmaxf(m + t2v[ct], 0.0f);  // relu(max+t) == max(relu(+t))
        v = fmaxf(v, __shfl_xor(v, 32, 64));  // merge complementary row halves
        if (l < 32) out[OFF_FEAT + (size_t)q * 128 + ct * 32 + l] = v;
      }
    }

    // ---- rotate pipeline registers ----
    xb = nxb;
    cx = ncx; cy = ncy; cz = ncz;
    ppx = nppx; ppy = nppy; ppz = nppz;
  }
}

extern "C" void kernel_launch(void* const* d_in, const int* in_sizes, int n_in,
                              void* d_out, int out_size, void* d_ws,
                              size_t ws_size, hipStream_t stream) {
  const float* xyz = (const float*)d_in[0];
  const float* features = (const float*)d_in[1];
  const int* inds = (const int*)d_in[2];
  const float* w0 = (const float*)d_in[3];
  const float* s0 = (const float*)d_in[4];
  const float* t0 = (const float*)d_in[5];
  const float* w1 = (const float*)d_in[6];
  const float* s1 = (const float*)d_in[7];
  const float* t1 = (const float*)d_in[8];
  const float* w2 = (const float*)d_in[9];
  const float* s2 = (const float*)d_in[10];
  const float* t2 = (const float*)d_in[11];
  float* out = (float*)d_out;

  const int nquery = BB * NPOINT;  // 16384
  ballq_kernel<<<nquery / 4, 256, 0, stream>>>(xyz, inds, out);
  // 2 waves/block * QPW queries each -> 1024 blocks = 4 blocks/CU
  mlp_mfma<<<nquery / (2 * QPW), 128, 0, stream>>>(
      xyz, features, inds, w0, s0, t0, w1, s1, t1, w2, s2, t2, out);
}

// Round 11
// 184.978 us; speedup vs baseline: 1.4122x; 1.2061x over previous
//
#include <hip/hip_runtime.h>

#define BB 8
#define NN 8192
#define NPOINT 2048
#define NSAMPLE 64
#define CIN 64
#define RADIUS 0.2f
#define R2 (RADIUS * RADIUS)

// d_out layout (flat floats, reference return order)
#define OFF_NEWXYZ 0
#define OFF_FEAT (BB * NPOINT * 3)
#define OFF_INDS (OFF_FEAT + BB * NPOINT * 128)
#define OFF_IDX (OFF_INDS + BB * NPOINT)

typedef _Float16 half8 __attribute__((ext_vector_type(8)));
typedef float floatx16 __attribute__((ext_vector_type(16)));

// Per-wave LDS slice (halves). P0=88 (K0=80+pad, stride 176B = 12 banks mod
// 32 -> near-conflict-free b128). P1=72 (144B = 4 banks mod 32). R6-proven:
// 83us mlp, 94K conflict cycles. Do NOT swizzle (R7/R8 regressions) and do
// NOT add LDS (R7: +256B crossed the 4-blocks/CU boundary).
#define P0 88
#define P1 72
#define X_LOC 0
#define H_LOC (64 * P0)                 // 5632
#define XH_WAVE (64 * P0 + 64 * P1)     // 10240 halves = 20480 B per wave
// one-time weight staging (block-shared, overlaps the wave slices):
#define WT0_S 0
#define WT1_S (64 * P0)
#define WT2_S (64 * P0 + 64 * P1)       // fits in 2*XH_WAVE

#define QPW 8  // queries per wave; 1024 blocks = 4 blocks/CU, no tail

// ---------------------------------------------------------------------------
// Kernel 1: ball query. High occupancy (4096 blocks, tiny LDS) hides the
// serial ballot chain — keep separate from the MLP kernel (R9: fusion at
// 8 waves/CU exposed ~110us of scan latency). Scatter hit indices into a
// per-wave LDS buffer (in-order DS, no barrier needed within a wave), then
// one coalesced float store per lane; padding resolved from LDS (kills the
// old global write->read round-trip).
// Distance formula must stay qq + nn - 2*dot (reference rounding).
// ---------------------------------------------------------------------------
__global__ __launch_bounds__(256) void ballq_kernel(
    const float* __restrict__ xyz, const int* __restrict__ inds,
    float* __restrict__ out) {
  __shared__ int sidx[4][NSAMPLE];  // 1 KB: 4 waves/block
  const int wq = (blockIdx.x * 256 + threadIdx.x) >> 6;  // query id
  const int lane = threadIdx.x & 63;
  const int wid = threadIdx.x >> 6;  // wave within block
  const int b = wq >> 11;            // NPOINT = 2048

  const float* xb = xyz + (size_t)b * NN * 3;
  const int ind = inds[wq];
  const float cx = xb[ind * 3 + 0];
  const float cy = xb[ind * 3 + 1];
  const float cz = xb[ind * 3 + 2];

  if (lane == 0) {
    out[OFF_NEWXYZ + (size_t)wq * 3 + 0] = cx;
    out[OFF_NEWXYZ + (size_t)wq * 3 + 1] = cy;
    out[OFF_NEWXYZ + (size_t)wq * 3 + 2] = cz;
    out[OFF_INDS + wq] = (float)ind;
  }

  const float qq = cx * cx + cy * cy + cz * cz;

  int cnt = 0;
  float ax[4], ay[4], az[4];
#pragma unroll
  for (int k = 0; k < 4; ++k) {
    const float* p = xb + (size_t)(k * 64 + lane) * 3;
    ax[k] = p[0];
    ay[k] = p[1];
    az[k] = p[2];
  }
  for (int j0 = 0; j0 < NN; j0 += 256) {
    float bx[4] = {0}, by[4] = {0}, bz[4] = {0};
    const int jn = j0 + 256;
    if (jn < NN) {  // prefetch next chunk while ballots run on current
#pragma unroll
      for (int k = 0; k < 4; ++k) {
        const float* p = xb + (size_t)(jn + k * 64 + lane) * 3;
        bx[k] = p[0];
        by[k] = p[1];
        bz[k] = p[2];
      }
    }
#pragma unroll
    for (int k = 0; k < 4; ++k) {  // k-major preserves point order
      const float nn_ = ax[k] * ax[k] + ay[k] * ay[k] + az[k] * az[k];
      const float dot = cx * ax[k] + cy * ay[k] + cz * az[k];
      const bool hit = (qq + nn_ - 2.0f * dot) < R2;
      const unsigned long long m = __ballot(hit);
      if (hit) {
        const int pos = cnt + (int)__popcll(m & ((1ull << lane) - 1ull));
        if (pos < NSAMPLE) sidx[wid][pos] = j0 + k * 64 + lane;
      }
      cnt += (int)__popcll(m);
    }
    if (cnt >= NSAMPLE) break;
#pragma unroll
    for (int k = 0; k < 4; ++k) {
      ax[k] = bx[k];
      ay[k] = by[k];
      az[k] = bz[k];
    }
  }
  // Pad with first hit (center always hits itself -> cnt >= 1; if cnt >= 64
  // all 64 slots were written). Same-wave DS ops are in-order: reads below
  // see the scatter writes above without a barrier.
  const int v = sidx[wid][lane < cnt ? lane : 0];
  out[OFF_IDX + (size_t)wq * NSAMPLE + lane] = (float)v;  // coalesced
}

// ---------------------------------------------------------------------------
// Kernel 2: barrier-free MFMA MLP — EXACT R6 structure (best measured:
// 83us, 94K conflicts, no scratch). 128-thread block = 2 independent waves,
// private LDS slices. Weights register-resident (s* folded; t0 as bias
// channel 67; t1/t2 column-indexed). A = activations (ds_read_b128 rows),
// B = weights; C cols = d (lane), rows = samples; L2 maxpool = register
// reduction + 1 shuffle. Do NOT add live state across layers (R10: +64 VGPR
// prefetch spilled to scratch, FETCH 64->202 MB).
// ---------------------------------------------------------------------------
__global__ __launch_bounds__(128, 2) void mlp_mfma(
    const float* __restrict__ xyz, const float* __restrict__ features,
    const int* __restrict__ inds,
    const float* __restrict__ w0, const float* __restrict__ s0,
    const float* __restrict__ t0, const float* __restrict__ w1,
    const float* __restrict__ s1, const float* __restrict__ t1,
    const float* __restrict__ w2, const float* __restrict__ s2,
    const float* __restrict__ t2, float* __restrict__ out) {
  __shared__ _Float16 sm[2 * XH_WAVE];  // 40960 B -> 4 blocks/CU, 8 waves/CU
  const int tid = threadIdx.x;
  const int w = tid >> 6;
  const int l = tid & 63;
  const int l31 = l & 31;
  const int h5 = l >> 5;
  const int koff = h5 * 8;  // fragment k-offset in halves

  // ---- stage folded weights into fragment-layout LDS (block-wide, once) ----
  {
    const int d = tid >> 1, hf = tid & 1;
    const float sd0 = s0[d], td0 = t0[d], sd1 = s1[d];
#pragma unroll
    for (int j = 0; j < 44; ++j) {
      const int c = hf * 44 + j;
      float v = 0.0f;
      if (c < 64) v = w0[(3 + c) * 64 + d] * sd0;        // feature channels
      else if (c < 67) v = w0[(c - 64) * 64 + d] * sd0;  // xyz channels
      else if (c == 67) v = td0;                         // bias channel
      sm[WT0_S + d * P0 + c] = (_Float16)v;
    }
#pragma unroll
    for (int j = 0; j < 32; ++j) {
      const int c = hf * 32 + j;
      sm[WT1_S + d * P1 + c] = (_Float16)(w1[c * 64 + d] * sd1);
    }
    const int ch = tid;  // 0..127
    const float sch = s2[ch];
#pragma unroll
    for (int c = 0; c < 64; ++c)
      sm[WT2_S + ch * P1 + c] = (_Float16)(w2[c * 128 + ch] * sch);
  }
  __syncthreads();

  // ---- hoist weight fragments + t vectors into registers ----
  half8 b0f[2][5], b1f[2][4], b2f[4][4];
#pragma unroll
  for (int nt = 0; nt < 2; ++nt)
#pragma unroll
    for (int ks = 0; ks < 5; ++ks)
      b0f[nt][ks] =
          *(const half8*)&sm[WT0_S + (nt * 32 + l31) * P0 + ks * 16 + koff];
#pragma unroll
  for (int nt = 0; nt < 2; ++nt)
#pragma unroll
    for (int ks = 0; ks < 4; ++ks)
      b1f[nt][ks] =
          *(const half8*)&sm[WT1_S + (nt * 32 + l31) * P1 + ks * 16 + koff];
#pragma unroll
  for (int ct = 0; ct < 4; ++ct)
#pragma unroll
    for (int ks = 0; ks < 4; ++ks)
      b2f[ct][ks] =
          *(const half8*)&sm[WT2_S + (ct * 32 + l31) * P1 + ks * 16 + koff];
  const float t1v0 = t1[l31];
  const float t1v1 = t1[32 + l31];
  float t2v[4];
#pragma unroll
  for (int ct = 0; ct < 4; ++ct) t2v[ct] = t2[ct * 32 + l31];
  __syncthreads();  // all fragment reads done before slices overwrite region

  _Float16* xbuf = sm + w * XH_WAVE + X_LOC;
  _Float16* hbuf = sm + w * XH_WAVE + H_LOC;
  // zero X K-pad halves 72..79 once (64..71 rewritten per query)
  {
    half8 z = {};
    *(half8*)&xbuf[l * P0 + 72] = z;
  }

  const int wq0 = (blockIdx.x * 2 + w) * QPW;
#pragma unroll 1
  for (int qi = 0; qi < QPW; ++qi) {
    const int q = wq0 + qi;
    const int b = q >> 11;

    // ---- gather + stage X (lane = sample) ----
    const int idxs = (int)out[OFF_IDX + (size_t)q * NSAMPLE + l];
    const float* xb = xyz + (size_t)b * NN * 3;
    const int ind = inds[q];
    const float cx = xb[ind * 3 + 0], cy = xb[ind * 3 + 1],
                cz = xb[ind * 3 + 2];
    const float ppx = xb[idxs * 3 + 0], ppy = xb[idxs * 3 + 1],
                ppz = xb[idxs * 3 + 2];
    const float4* fr =
        (const float4*)(features + ((size_t)b * NN + (size_t)idxs) * CIN);
    float4 f[16];
#pragma unroll
    for (int u = 0; u < 16; ++u) f[u] = fr[u];
#pragma unroll
    for (int u = 0; u < 8; ++u) {
      half8 hv;
      hv[0] = (_Float16)f[2 * u].x;
      hv[1] = (_Float16)f[2 * u].y;
      hv[2] = (_Float16)f[2 * u].z;
      hv[3] = (_Float16)f[2 * u].w;
      hv[4] = (_Float16)f[2 * u + 1].x;
      hv[5] = (_Float16)f[2 * u + 1].y;
      hv[6] = (_Float16)f[2 * u + 1].z;
      hv[7] = (_Float16)f[2 * u + 1].w;
      *(half8*)&xbuf[l * P0 + u * 8] = hv;
    }
    {
      half8 xv = {};
      xv[0] = (_Float16)((ppx - cx) * 5.0f);
      xv[1] = (_Float16)((ppy - cy) * 5.0f);
      xv[2] = (_Float16)((ppz - cz) * 5.0f);
      xv[3] = (_Float16)1.0f;  // bias channel 67
      *(half8*)&xbuf[l * P0 + 64] = xv;
    }

    // ---- L0: H0 = relu(X @ W0' + t0) (K=80, bias via channel 67) ----
    {
      half8 xa[2][5];
#pragma unroll
      for (int st = 0; st < 2; ++st)
#pragma unroll
        for (int ks = 0; ks < 5; ++ks)
          xa[st][ks] =
              *(const half8*)&xbuf[(st * 32 + l31) * P0 + ks * 16 + koff];
#pragma unroll
      for (int nt = 0; nt < 2; ++nt)
#pragma unroll
        for (int st = 0; st < 2; ++st) {
          floatx16 acc;
#pragma unroll
          for (int i = 0; i < 16; ++i) acc[i] = 0.0f;
#pragma unroll
          for (int ks = 0; ks < 5; ++ks)
            acc = __builtin_amdgcn_mfma_f32_32x32x16_f16(xa[st][ks],
                                                         b0f[nt][ks], acc,
                                                         0, 0, 0);
#pragma unroll
          for (int reg = 0; reg < 16; ++reg) {
            const int row = st * 32 + (reg & 3) + 8 * (reg >> 2) + 4 * h5;
            hbuf[row * P1 + nt * 32 + l31] = (_Float16)fmaxf(acc[reg], 0.0f);
          }
        }
    }

    // ---- L1: H1 = relu(H0 @ W1' + t1), written into xbuf cols 0..63 ----
    {
      half8 ha[2][4];
#pragma unroll
      for (int st = 0; st < 2; ++st)
#pragma unroll
        for (int ks = 0; ks < 4; ++ks)
          ha[st][ks] =
              *(const half8*)&hbuf[(st * 32 + l31) * P1 + ks * 16 + koff];
#pragma unroll
      for (int nt = 0; nt < 2; ++nt) {
        const float tt = nt ? t1v1 : t1v0;
#pragma unroll
        for (int st = 0; st < 2; ++st) {
          floatx16 acc;
#pragma unroll
          for (int i = 0; i < 16; ++i) acc[i] = 0.0f;
#pragma unroll
          for (int ks = 0; ks < 4; ++ks)
            acc = __builtin_amdgcn_mfma_f32_32x32x16_f16(ha[st][ks],
                                                         b1f[nt][ks], acc,
                                                         0, 0, 0);
#pragma unroll
          for (int reg = 0; reg < 16; ++reg) {
            const int row = st * 32 + (reg & 3) + 8 * (reg >> 2) + 4 * h5;
            xbuf[row * P0 + nt * 32 + l31] =
                (_Float16)fmaxf(acc[reg] + tt, 0.0f);
          }
        }
      }
    }

    // ---- L2: Y = H1 @ W2' (lane owns d2 column), fused maxpool ----
    {
      half8 h1a[2][4];
#pragma unroll
      for (int st = 0; st < 2; ++st)
#pragma unroll
        for (int ks = 0; ks < 4; ++ks)
          h1a[st][ks] =
              *(const half8*)&xbuf[(st * 32 + l31) * P0 + ks * 16 + koff];
#pragma unroll
      for (int ct = 0; ct < 4; ++ct) {
        floatx16 aA, aB;
#pragma unroll
        for (int i = 0; i < 16; ++i) {
          aA[i] = 0.0f;
          aB[i] = 0.0f;
        }
#pragma unroll
        for (int ks = 0; ks < 4; ++ks) {
          aA = __builtin_amdgcn_mfma_f32_32x32x16_f16(h1a[0][ks], b2f[ct][ks],
                                                      aA, 0, 0, 0);
          aB = __builtin_amdgcn_mfma_f32_32x32x16_f16(h1a[1][ks], b2f[ct][ks],
                                                      aB, 0, 0, 0);
        }
        float m = fmaxf(aA[0], aB[0]);
#pragma unroll
        for (int i = 1; i < 16; ++i) m = fmaxf(m, fmaxf(aA[i], aB[i]));
        float v = fmaxf(m + t2v[ct], 0.0f);  // relu(max+t) == max(relu(+t))
        v = fmaxf(v, __shfl_xor(v, 32, 64));  // merge complementary row halves
        if (l < 32) out[OFF_FEAT + (size_t)q * 128 + ct * 32 + l] = v;
      }
    }
  }
}

extern "C" void kernel_launch(void* const* d_in, const int* in_sizes, int n_in,
                              void* d_out, int out_size, void* d_ws,
                              size_t ws_size, hipStream_t stream) {
  const float* xyz = (const float*)d_in[0];
  const float* features = (const float*)d_in[1];
  const int* inds = (const int*)d_in[2];
  const float* w0 = (const float*)d_in[3];
  const float* s0 = (const float*)d_in[4];
  const float* t0 = (const float*)d_in[5];
  const float* w1 = (const float*)d_in[6];
  const float* s1 = (const float*)d_in[7];
  const float* t1 = (const float*)d_in[8];
  const float* w2 = (const float*)d_in[9];
  const float* s2 = (const float*)d_in[10];
  const float* t2 = (const float*)d_in[11];
  float* out = (float*)d_out;

  const int nquery = BB * NPOINT;  // 16384
  ballq_kernel<<<nquery / 4, 256, 0, stream>>>(xyz, inds, out);
  // 2 waves/block * QPW queries each -> 1024 blocks = 4 blocks/CU
  mlp_mfma<<<nquery / (2 * QPW), 128, 0, stream>>>(
      xyz, features, inds, w0, s0, t0, w1, s1, t1, w2, s2, t2, out);
}

// Round 12
// 173.964 us; speedup vs baseline: 1.5016x; 1.0633x over previous
//
#include <hip/hip_runtime.h>

#define BB 8
#define NN 8192
#define NPOINT 2048
#define NSAMPLE 64
#define CIN 64
#define RADIUS 0.2f
#define R2 (RADIUS * RADIUS)

// d_out layout (flat floats, reference return order)
#define OFF_NEWXYZ 0
#define OFF_FEAT (BB * NPOINT * 3)
#define OFF_INDS (OFF_FEAT + BB * NPOINT * 128)
#define OFF_IDX (OFF_INDS + BB * NPOINT)

typedef _Float16 half8 __attribute__((ext_vector_type(8)));
typedef _Float16 half4 __attribute__((ext_vector_type(4)));
typedef __fp16 f16x2 __attribute__((ext_vector_type(2)));
typedef float floatx16 __attribute__((ext_vector_type(16)));

// Per-wave LDS slice (halves). P0=88, P1=72 (R6-proven: no swizzle, no extra
// LDS — R7 showed +256B crosses the 4-blocks/CU boundary).
#define P0 88
#define P1 72
#define X_LOC 0
#define H_LOC (64 * P0)                 // 5632
#define XH_WAVE (64 * P0 + 64 * P1)     // 10240 halves = 20480 B per wave
#define WT0_S 0
#define WT1_S (64 * P0)
#define WT2_S (64 * P0 + 64 * P1)       // fits in 2*XH_WAVE

#define QPW 8  // queries per wave; 1024 blocks = 4 blocks/CU, no tail

// ---------------------------------------------------------------------------
// Kernel 1: ball query, TWO queries per wave (pair shares a batch since
// pairs (2w,2w+1) never straddle the 2048 boundary): one stream of point
// loads feeds two independent distance/ballot chains -> 2x latency-hiding
// chains per CU, half the candidate traffic. LDS scatter + coalesced store
// (R11). Distance formula must stay qq + nn - 2*dot (reference rounding).
// ---------------------------------------------------------------------------
__global__ __launch_bounds__(256) void ballq_kernel(
    const float* __restrict__ xyz, const int* __restrict__ inds,
    float* __restrict__ out) {
  __shared__ int sidx[4][2][NSAMPLE];  // 2 KB: 4 waves x 2 queries
  const int wave = (blockIdx.x * 256 + threadIdx.x) >> 6;
  const int lane = threadIdx.x & 63;
  const int wid = threadIdx.x >> 6;
  const int q0 = wave * 2, q1 = q0 + 1;
  const int b = q0 >> 11;  // NPOINT = 2048; pair shares batch

  const float* xb = xyz + (size_t)b * NN * 3;
  const int i0 = inds[q0], i1 = inds[q1];
  const float c0x = xb[i0 * 3 + 0], c0y = xb[i0 * 3 + 1], c0z = xb[i0 * 3 + 2];
  const float c1x = xb[i1 * 3 + 0], c1y = xb[i1 * 3 + 1], c1z = xb[i1 * 3 + 2];

  if (lane < 2) {
    const int qq_ = lane ? q1 : q0;
    const int ii = lane ? i1 : i0;
    out[OFF_NEWXYZ + (size_t)qq_ * 3 + 0] = lane ? c1x : c0x;
    out[OFF_NEWXYZ + (size_t)qq_ * 3 + 1] = lane ? c1y : c0y;
    out[OFF_NEWXYZ + (size_t)qq_ * 3 + 2] = lane ? c1z : c0z;
    out[OFF_INDS + qq_] = (float)ii;
  }

  const float qq0 = c0x * c0x + c0y * c0y + c0z * c0z;
  const float qq1 = c1x * c1x + c1y * c1y + c1z * c1z;

  int cnt0 = 0, cnt1 = 0;
  float ax[4], ay[4], az[4];
#pragma unroll
  for (int k = 0; k < 4; ++k) {
    const float* p = xb + (size_t)(k * 64 + lane) * 3;
    ax[k] = p[0];
    ay[k] = p[1];
    az[k] = p[2];
  }
  for (int j0 = 0; j0 < NN; j0 += 256) {
    float bx[4] = {0}, by[4] = {0}, bz[4] = {0};
    const int jn = j0 + 256;
    if (jn < NN) {  // prefetch next chunk while ballots run on current
#pragma unroll
      for (int k = 0; k < 4; ++k) {
        const float* p = xb + (size_t)(jn + k * 64 + lane) * 3;
        bx[k] = p[0];
        by[k] = p[1];
        bz[k] = p[2];
      }
    }
#pragma unroll
    for (int k = 0; k < 4; ++k) {  // k-major preserves point order
      const int j = j0 + k * 64 + lane;
      const float nn_ = ax[k] * ax[k] + ay[k] * ay[k] + az[k] * az[k];
      const float dot0 = c0x * ax[k] + c0y * ay[k] + c0z * az[k];
      const float dot1 = c1x * ax[k] + c1y * ay[k] + c1z * az[k];
      const bool hit0 = (qq0 + nn_ - 2.0f * dot0) < R2;
      const bool hit1 = (qq1 + nn_ - 2.0f * dot1) < R2;
      const unsigned long long m0 = __ballot(hit0);
      const unsigned long long m1 = __ballot(hit1);
      if (hit0) {
        const int pos = cnt0 + (int)__popcll(m0 & ((1ull << lane) - 1ull));
        if (pos < NSAMPLE) sidx[wid][0][pos] = j;
      }
      if (hit1) {
        const int pos = cnt1 + (int)__popcll(m1 & ((1ull << lane) - 1ull));
        if (pos < NSAMPLE) sidx[wid][1][pos] = j;
      }
      cnt0 += (int)__popcll(m0);
      cnt1 += (int)__popcll(m1);
    }
    if (cnt0 >= NSAMPLE && cnt1 >= NSAMPLE) break;
#pragma unroll
    for (int k = 0; k < 4; ++k) {
      ax[k] = bx[k];
      ay[k] = by[k];
      az[k] = bz[k];
    }
  }
  // Pad with first hit (center always hits itself -> cnt >= 1). Same-wave DS
  // ops are in-order: reads below see the scatter writes without a barrier.
  const int v0 = sidx[wid][0][lane < cnt0 ? lane : 0];
  out[OFF_IDX + (size_t)q0 * NSAMPLE + lane] = (float)v0;
  const int v1 = sidx[wid][1][lane < cnt1 ? lane : 0];
  out[OFF_IDX + (size_t)q1 * NSAMPLE + lane] = (float)v1;
}

// ---------------------------------------------------------------------------
// Kernel 2: barrier-free MFMA MLP (R6 core) + two chain cuts:
//  (a) grouped coalesced feature gather: lane l fetches row (l>>2)+16(i&3)
//      chunk (l&3)+4(i>>2) -> 4 consecutive lanes share one 64B line
//      (16 lines/instr vs 64); row index via __shfl of the per-lane idx.
//  (b) next-query idx / center / pp-xyz prefetch (8 regs, issued >=1000cyc
//      ahead). Do NOT prefetch features (R10: +64 regs spilled to scratch).
// ---------------------------------------------------------------------------
__global__ __launch_bounds__(128, 2) void mlp_mfma(
    const float* __restrict__ xyz, const float* __restrict__ features,
    const int* __restrict__ inds,
    const float* __restrict__ w0, const float* __restrict__ s0,
    const float* __restrict__ t0, const float* __restrict__ w1,
    const float* __restrict__ s1, const float* __restrict__ t1,
    const float* __restrict__ w2, const float* __restrict__ s2,
    const float* __restrict__ t2, float* __restrict__ out) {
  __shared__ _Float16 sm[2 * XH_WAVE];  // 40960 B -> 4 blocks/CU, 8 waves/CU
  const int tid = threadIdx.x;
  const int w = tid >> 6;
  const int l = tid & 63;
  const int l31 = l & 31;
  const int h5 = l >> 5;
  const int koff = h5 * 8;  // fragment k-offset in halves

  // ---- stage folded weights into fragment-layout LDS (block-wide, once) ----
  {
    const int d = tid >> 1, hf = tid & 1;
    const float sd0 = s0[d], td0 = t0[d], sd1 = s1[d];
#pragma unroll
    for (int j = 0; j < 44; ++j) {
      const int c = hf * 44 + j;
      float v = 0.0f;
      if (c < 64) v = w0[(3 + c) * 64 + d] * sd0;        // feature channels
      else if (c < 67) v = w0[(c - 64) * 64 + d] * sd0;  // xyz channels
      else if (c == 67) v = td0;                         // bias channel
      sm[WT0_S + d * P0 + c] = (_Float16)v;
    }
#pragma unroll
    for (int j = 0; j < 32; ++j) {
      const int c = hf * 32 + j;
      sm[WT1_S + d * P1 + c] = (_Float16)(w1[c * 64 + d] * sd1);
    }
    const int ch = tid;  // 0..127
    const float sch = s2[ch];
#pragma unroll
    for (int c = 0; c < 64; ++c)
      sm[WT2_S + ch * P1 + c] = (_Float16)(w2[c * 128 + ch] * sch);
  }
  __syncthreads();

  // ---- hoist weight fragments + t vectors into registers ----
  half8 b0f[2][5], b1f[2][4], b2f[4][4];
#pragma unroll
  for (int nt = 0; nt < 2; ++nt)
#pragma unroll
    for (int ks = 0; ks < 5; ++ks)
      b0f[nt][ks] =
          *(const half8*)&sm[WT0_S + (nt * 32 + l31) * P0 + ks * 16 + koff];
#pragma unroll
  for (int nt = 0; nt < 2; ++nt)
#pragma unroll
    for (int ks = 0; ks < 4; ++ks)
      b1f[nt][ks] =
          *(const half8*)&sm[WT1_S + (nt * 32 + l31) * P1 + ks * 16 + koff];
#pragma unroll
  for (int ct = 0; ct < 4; ++ct)
#pragma unroll
    for (int ks = 0; ks < 4; ++ks)
      b2f[ct][ks] =
          *(const half8*)&sm[WT2_S + (ct * 32 + l31) * P1 + ks * 16 + koff];
  const float t1v0 = t1[l31];
  const float t1v1 = t1[32 + l31];
  float t2v[4];
#pragma unroll
  for (int ct = 0; ct < 4; ++ct) t2v[ct] = t2[ct * 32 + l31];
  __syncthreads();  // all fragment reads done before slices overwrite region

  _Float16* xbuf = sm + w * XH_WAVE + X_LOC;
  _Float16* hbuf = sm + w * XH_WAVE + H_LOC;
  // zero X K-pad halves 72..79 once (64..71 rewritten per query)
  {
    half8 z = {};
    *(half8*)&xbuf[l * P0 + 72] = z;
  }

  const int wq0 = (blockIdx.x * 2 + w) * QPW;
  const int b = wq0 >> 11;  // all QPW queries share one batch (wq0 % 8 == 0)
  const float* xb = xyz + (size_t)b * NN * 3;
  const float* fbase = features + (size_t)b * NN * CIN;

  // ---- prologue: first query's idx / center / pp ----
  int myidx = (int)out[OFF_IDX + (size_t)wq0 * NSAMPLE + l];
  int indv = inds[wq0];
  float cx = xb[indv * 3 + 0], cy = xb[indv * 3 + 1], cz = xb[indv * 3 + 2];
  float ppx = xb[myidx * 3 + 0], ppy = xb[myidx * 3 + 1],
        ppz = xb[myidx * 3 + 2];

#pragma unroll 1
  for (int qi = 0; qi < QPW; ++qi) {
    const int q = wq0 + qi;
    const int nq = (qi + 1 < QPW) ? q + 1 : q;  // clamp: redundant reload ok

    // ---- grouped coalesced feature gather (16 lines/instr) ----
    float4 g[16];
#pragma unroll
    for (int i = 0; i < 16; ++i) {
      const int s = (l >> 2) + 16 * (i & 3);
      const int c = (l & 3) + 4 * (i >> 2);
      const int sidx = __shfl(myidx, s, 64);
      g[i] = *(const float4*)(fbase + (size_t)sidx * CIN + 4 * c);
    }
    // issue next query's idx + inds loads (consumed after L0 / at rotate)
    const float fni = out[OFF_IDX + (size_t)nq * NSAMPLE + l];
    const int nindv = inds[nq];

    // ---- stage X ----
#pragma unroll
    for (int i = 0; i < 16; ++i) {
      const int s = (l >> 2) + 16 * (i & 3);
      const int c = (l & 3) + 4 * (i >> 2);
      union {
        half4 v;
        f16x2 p[2];
      } hv;
      hv.p[0] = __builtin_amdgcn_cvt_pkrtz(g[i].x, g[i].y);
      hv.p[1] = __builtin_amdgcn_cvt_pkrtz(g[i].z, g[i].w);
      *(half4*)&xbuf[s * P0 + 4 * c] = hv.v;
    }
    {
      union {
        half8 v;
        f16x2 p[4];
      } xv;
      xv.p[0] =
          __builtin_amdgcn_cvt_pkrtz((ppx - cx) * 5.0f, (ppy - cy) * 5.0f);
      xv.p[1] = __builtin_amdgcn_cvt_pkrtz((ppz - cz) * 5.0f, 1.0f);  // bias
      xv.p[2] = __builtin_amdgcn_cvt_pkrtz(0.0f, 0.0f);
      xv.p[3] = __builtin_amdgcn_cvt_pkrtz(0.0f, 0.0f);
      *(half8*)&xbuf[l * P0 + 64] = xv.v;
    }

    // ---- L0: H0 = relu(X @ W0' + t0) (K=80, bias via channel 67) ----
    {
      half8 xa[2][5];
#pragma unroll
      for (int st = 0; st < 2; ++st)
#pragma unroll
        for (int ks = 0; ks < 5; ++ks)
          xa[st][ks] =
              *(const half8*)&xbuf[(st * 32 + l31) * P0 + ks * 16 + koff];
#pragma unroll
      for (int nt = 0; nt < 2; ++nt)
#pragma unroll
        for (int st = 0; st < 2; ++st) {
          floatx16 acc;
#pragma unroll
          for (int i = 0; i < 16; ++i) acc[i] = 0.0f;
#pragma unroll
          for (int ks = 0; ks < 5; ++ks)
            acc = __builtin_amdgcn_mfma_f32_32x32x16_f16(xa[st][ks],
                                                         b0f[nt][ks], acc,
                                                         0, 0, 0);
#pragma unroll
          for (int reg = 0; reg < 16; ++reg) {
            const int row = st * 32 + (reg & 3) + 8 * (reg >> 2) + 4 * h5;
            hbuf[row * P1 + nt * 32 + l31] = (_Float16)fmaxf(acc[reg], 0.0f);
          }
        }
    }

    // ---- issue next query's center + pp loads (covered by L1+L2) ----
    const int nidxs = (int)fni;
    const float ncx = xb[nindv * 3 + 0];
    const float ncy = xb[nindv * 3 + 1];
    const float ncz = xb[nindv * 3 + 2];
    const float nppx = xb[nidxs * 3 + 0];
    const float nppy = xb[nidxs * 3 + 1];
    const float nppz = xb[nidxs * 3 + 2];

    // ---- L1: H1 = relu(H0 @ W1' + t1), written into xbuf cols 0..63 ----
    {
      half8 ha[2][4];
#pragma unroll
      for (int st = 0; st < 2; ++st)
#pragma unroll
        for (int ks = 0; ks < 4; ++ks)
          ha[st][ks] =
              *(const half8*)&hbuf[(st * 32 + l31) * P1 + ks * 16 + koff];
#pragma unroll
      for (int nt = 0; nt < 2; ++nt) {
        const float tt = nt ? t1v1 : t1v0;
#pragma unroll
        for (int st = 0; st < 2; ++st) {
          floatx16 acc;
#pragma unroll
          for (int i = 0; i < 16; ++i) acc[i] = 0.0f;
#pragma unroll
          for (int ks = 0; ks < 4; ++ks)
            acc = __builtin_amdgcn_mfma_f32_32x32x16_f16(ha[st][ks],
                                                         b1f[nt][ks], acc,
                                                         0, 0, 0);
#pragma unroll
          for (int reg = 0; reg < 16; ++reg) {
            const int row = st * 32 + (reg & 3) + 8 * (reg >> 2) + 4 * h5;
            xbuf[row * P0 + nt * 32 + l31] =
                (_Float16)fmaxf(acc[reg] + tt, 0.0f);
          }
        }
      }
    }

    // ---- L2: Y = H1 @ W2' (lane owns d2 column), fused maxpool ----
    {
      half8 h1a[2][4];
#pragma unroll
      for (int st = 0; st < 2; ++st)
#pragma unroll
        for (int ks = 0; ks < 4; ++ks)
          h1a[st][ks] =
              *(const half8*)&xbuf[(st * 32 + l31) * P0 + ks * 16 + koff];
#pragma unroll
      for (int ct = 0; ct < 4; ++ct) {
        floatx16 aA, aB;
#pragma unroll
        for (int i = 0; i < 16; ++i) {
          aA[i] = 0.0f;
          aB[i] = 0.0f;
        }
#pragma unroll
        for (int ks = 0; ks < 4; ++ks) {
          aA = __builtin_amdgcn_mfma_f32_32x32x16_f16(h1a[0][ks], b2f[ct][ks],
                                                      aA, 0, 0, 0);
          aB = __builtin_amdgcn_mfma_f32_32x32x16_f16(h1a[1][ks], b2f[ct][ks],
                                                      aB, 0, 0, 0);
        }
        float m = fmaxf(aA[0], aB[0]);
#pragma unroll
        for (int i = 1; i < 16; ++i) m = fmaxf(m, fmaxf(aA[i], aB[i]));
        float v = fmaxf(m + t2v[ct], 0.0f);  // relu(max+t) == max(relu(+t))
        v = fmaxf(v, __shfl_xor(v, 32, 64));  // merge complementary row halves
        if (l < 32) out[OFF_FEAT + (size_t)q * 128 + ct * 32 + l] = v;
      }
    }

    // ---- rotate pipeline registers ----
    myidx = nidxs;
    cx = ncx; cy = ncy; cz = ncz;
    ppx = nppx; ppy = nppy; ppz = nppz;
  }
}

extern "C" void kernel_launch(void* const* d_in, const int* in_sizes, int n_in,
                              void* d_out, int out_size, void* d_ws,
                              size_t ws_size, hipStream_t stream) {
  const float* xyz = (const float*)d_in[0];
  const float* features = (const float*)d_in[1];
  const int* inds = (const int*)d_in[2];
  const float* w0 = (const float*)d_in[3];
  const float* s0 = (const float*)d_in[4];
  const float* t0 = (const float*)d_in[5];
  const float* w1 = (const float*)d_in[6];
  const float* s1 = (const float*)d_in[7];
  const float* t1 = (const float*)d_in[8];
  const float* w2 = (const float*)d_in[9];
  const float* s2 = (const float*)d_in[10];
  const float* t2 = (const float*)d_in[11];
  float* out = (float*)d_out;

  const int nquery = BB * NPOINT;  // 16384
  // ballq: 2 queries per wave -> 8192 waves -> 2048 blocks
  ballq_kernel<<<nquery / 8, 256, 0, stream>>>(xyz, inds, out);
  // mlp: 2 waves/block * QPW queries each -> 1024 blocks = 4 blocks/CU
  mlp_mfma<<<nquery / (2 * QPW), 128, 0, stream>>>(
      xyz, features, inds, w0, s0, t0, w1, s1, t1, w2, s2, t2, out);
}